// Round 11
// baseline (3373.322 us; speedup 1.0000x reference)
//
#include <hip/hip_runtime.h>

#define IDIM 512
#define MIXD 32
#define HID 96
#define BB 256
#define TT 512

typedef float f32x2 __attribute__((ext_vector_type(2)));
typedef float f32x4 __attribute__((ext_vector_type(4)));

// v_exp_f32: D = 2^S0
#define EXP2(x) __builtin_amdgcn_exp2f(x)

// DPP row_shl:N add on the VALU pipe (not the shared LDS pipe).
template <int CTRL>
__device__ __forceinline__ float dpp_shl_add(float x) {
    int m = __builtin_amdgcn_update_dpp(0, __float_as_int(x), CTRL, 0xf, 0xf, true);
    return x + __int_as_float(m);
}
// Reduce 8 consecutive lanes (octet) into the octet's lane 0.
__device__ __forceinline__ float octet_reduce_lane0(float x) {
    x = dpp_shl_add<0x104>(x);   // row_shl:4
    x = dpp_shl_add<0x102>(x);   // row_shl:2
    x = dpp_shl_add<0x101>(x);   // row_shl:1
    return x;
}

// ---------------- fused mix + GRU scan + head: 1 batch element per block ----
// 512 threads = 8 waves. waves 0-3 = consumer (R9 scan structure), waves 4-7
// = producer (z = W_mix·x straight into the LDS chunk dbuf; z never touches
// HBM). R10 failed on a 128-VGPR cap -> 30 MB/dispatch spill traffic in the
// step loop; fixes here: (1) __launch_bounds__(512,1) lifts the cap, (2) the
// prologue's temp W-slice dies before scan weights load and producers RELOAD
// wp after the prologue (disjoint live ranges), (3) producers double-buffer
// the x row so the per-barrier vmcnt drain overlaps compute.
__global__ __launch_bounds__(512, 1) void k_fused(const float* __restrict__ x,
                                                  const float* __restrict__ Wmix,
                                                  const float* __restrict__ Wih,
                                                  const float* __restrict__ Whh,
                                                  const float* __restrict__ bih,
                                                  const float* __restrict__ bhh,
                                                  const float* __restrict__ Whead,
                                                  const float* __restrict__ bhead,
                                                  float* __restrict__ y) {
    const int b    = blockIdx.x;
    const int tid  = threadIdx.x;
    const bool cons = tid < 256;
    const float L  = 1.4426950408889634f;   // log2(e)
    const float L2 = 2.8853900817779268f;   // 2*log2(e)

    __shared__ __align__(16) float sz[2][256 * MIXD];  // 64 KB z chunk dbuf
    __shared__ __align__(16) float shp[2][HID];        // h ping-pong
    __shared__ __align__(16) float szn[MIXD];

    const int p  = tid & 255;
    const int pm = p >> 3, pks = p & 7;

    if (tid < HID) shp[0][tid] = 0.f;   // h0 = 0 (visible after prologue barrier)

    // ---- prologue: ALL threads produce chunk 0 with a TEMP W slice that
    //      dies here (consumers rows 0..127, producers rows 128..255).
    {
        f32x2 wt[32];
        #pragma unroll
        for (int u = 0; u < 16; ++u) {
            f32x4 v = *(const f32x4*)(Wmix + (size_t)pm * IDIM + 64 * pks + 4 * u);
            wt[2*u] = v.xy; wt[2*u+1] = v.zw;
        }
        const int r0 = cons ? 0 : 128;
        const float* xb = x + (size_t)b * TT * IDIM + 64 * pks;
        f32x4 xv[16], xn[16];
        #pragma unroll
        for (int u = 0; u < 16; ++u)
            xv[u] = *(const f32x4*)(xb + (size_t)r0 * IDIM + 4 * u);
        for (int rr = 0; rr < 128; ++rr) {
            if (rr + 1 < 128) {
                #pragma unroll
                for (int u = 0; u < 16; ++u)
                    xn[u] = *(const f32x4*)(xb + (size_t)(r0 + rr + 1) * IDIM + 4 * u);
            }
            f32x2 acc = {0.f, 0.f};
            #pragma unroll
            for (int u = 0; u < 16; ++u) {
                acc = __builtin_elementwise_fma(wt[2*u],   xv[u].xy, acc);
                acc = __builtin_elementwise_fma(wt[2*u+1], xv[u].zw, acc);
            }
            float s = octet_reduce_lane0(acc.x + acc.y);
            if (pks == 0) sz[0][(r0 + rr) * MIXD + pm] = s;
            #pragma unroll
            for (int u = 0; u < 16; ++u) xv[u] = xn[u];
        }
    }

    // ---- post-prologue register sets (disjoint from prologue temps) ----
    const int j0 = tid >> 3;      // consumers: 0..31
    const int o  = tid & 7;
    f32x2 whr[3][6], whu[3][6], whn[3][6], wir[3][2], wiu[3][2], win[3][2];
    float br[3], bu[3], bxn[3], bhn[3];
    float hown[3] = {0.f, 0.f, 0.f};
    f32x2 wp[32];                 // producers: persistent mix-W slice
    f32x4 pxv[16];                // producers: x row double buffer (front)

    if (cons) {
        #pragma unroll
        for (int i = 0; i < 3; ++i) {
            const int j = j0 + 32 * i;
            #pragma unroll
            for (int c = 0; c < 3; ++c) {
                f32x4 v = *(const f32x4*)(Whh + (size_t)(j        ) * HID + o * 12 + c * 4);
                v *= L;  whr[i][2*c] = v.xy; whr[i][2*c+1] = v.zw;
            }
            #pragma unroll
            for (int c = 0; c < 3; ++c) {
                f32x4 v = *(const f32x4*)(Whh + (size_t)(j +   HID) * HID + o * 12 + c * 4);
                v *= L;  whu[i][2*c] = v.xy; whu[i][2*c+1] = v.zw;
            }
            #pragma unroll
            for (int c = 0; c < 3; ++c) {
                f32x4 v = *(const f32x4*)(Whh + (size_t)(j + 2*HID) * HID + o * 12 + c * 4);
                v *= L2; whn[i][2*c] = v.xy; whn[i][2*c+1] = v.zw;
            }
            {
                f32x4 v = *(const f32x4*)(Wih + (size_t)(j        ) * MIXD + o * 4);
                v *= L;  wir[i][0] = v.xy; wir[i][1] = v.zw;
            }
            {
                f32x4 v = *(const f32x4*)(Wih + (size_t)(j +   HID) * MIXD + o * 4);
                v *= L;  wiu[i][0] = v.xy; wiu[i][1] = v.zw;
            }
            {
                f32x4 v = *(const f32x4*)(Wih + (size_t)(j + 2*HID) * MIXD + o * 4);
                v *= L2; win[i][0] = v.xy; win[i][1] = v.zw;
            }
            br[i]  = (o == 0) ? L  * (bih[j]       + bhh[j])       : 0.f;
            bu[i]  = (o == 0) ? L  * (bih[j + HID] + bhh[j + HID]) : 0.f;
            bxn[i] = (o == 0) ? L2 * bih[j + 2*HID] : 0.f;
            bhn[i] = (o == 0) ? L2 * bhh[j + 2*HID] : 0.f;
        }
    } else {
        // producers reload wp (fresh live range) + preload x row 256
        #pragma unroll
        for (int u = 0; u < 16; ++u) {
            f32x4 v = *(const f32x4*)(Wmix + (size_t)pm * IDIM + 64 * pks + 4 * u);
            wp[2*u] = v.xy; wp[2*u+1] = v.zw;
        }
        const float* xr = x + ((size_t)b * TT + 256) * IDIM + 64 * pks;
        #pragma unroll
        for (int u = 0; u < 16; ++u) pxv[u] = *(const f32x4*)(xr + 4 * u);
    }
    __syncthreads();   // chunk 0 + h0 visible

    // ---- main loop: 2 chunks x 256 steps, one barrier per step ----
    for (int c = 0; c < 2; ++c) {
        const float* zbuf = sz[c & 1];
        for (int tt = 0; tt < 256; ++tt) {
            if (cons) {
                const int t = (c << 8) + tt;
                const float* hr = shp[t & 1];
                float*       hw = shp[(t + 1) & 1];

                const f32x4 z4 = *(const f32x4*)(zbuf + tt * MIXD + o * 4);
                const f32x4 h0 = *(const f32x4*)(hr + o * 12);
                const f32x4 h1 = *(const f32x4*)(hr + o * 12 + 4);
                const f32x4 h2 = *(const f32x4*)(hr + o * 12 + 8);
                const f32x2 hh[6] = { h0.xy, h0.zw, h1.xy, h1.zw, h2.xy, h2.zw };

                float hv[3];
                #pragma unroll
                for (int i = 0; i < 3; ++i) {
                    f32x2 aR  = {br[i],  0.f}, aU  = {bu[i],  0.f};
                    f32x2 aXN = {bxn[i], 0.f}, aHN = {bhn[i], 0.f};

                    aR  = __builtin_elementwise_fma(wir[i][0], z4.xy, aR);
                    aR  = __builtin_elementwise_fma(wir[i][1], z4.zw, aR);
                    aU  = __builtin_elementwise_fma(wiu[i][0], z4.xy, aU);
                    aU  = __builtin_elementwise_fma(wiu[i][1], z4.zw, aU);
                    aXN = __builtin_elementwise_fma(win[i][0], z4.xy, aXN);
                    aXN = __builtin_elementwise_fma(win[i][1], z4.zw, aXN);

                    #pragma unroll
                    for (int k = 0; k < 6; ++k) {
                        aR  = __builtin_elementwise_fma(whr[i][k], hh[k], aR);
                        aU  = __builtin_elementwise_fma(whu[i][k], hh[k], aU);
                        aHN = __builtin_elementwise_fma(whn[i][k], hh[k], aHN);
                    }

                    float sR  = octet_reduce_lane0(aR.x  + aR.y);
                    float sU  = octet_reduce_lane0(aU.x  + aU.y);
                    float sXN = octet_reduce_lane0(aXN.x + aXN.y);
                    float sHN = octet_reduce_lane0(aHN.x + aHN.y);

                    float r = __builtin_amdgcn_rcpf(1.f + EXP2(-sR));
                    float u = __builtin_amdgcn_rcpf(1.f + EXP2(-sU));
                    float n = 1.f - 2.f * __builtin_amdgcn_rcpf(1.f + EXP2(sXN + r * sHN));
                    hv[i] = u * (hown[i] - n) + n;   // lane0 correct; others garbage
                    hown[i] = hv[i];
                }
                if (o == 0) {
                    hw[j0]      = hv[0];
                    hw[j0 + 32] = hv[1];
                    hw[j0 + 64] = hv[2];
                }
            } else if (c == 0) {
                // issue NEXT row's loads first (drain at barrier overlaps
                // this row's compute), then compute row tt from pxv
                f32x4 xn[16];
                const bool more = (tt + 1 < 256);
                if (more) {
                    const float* xr = x + ((size_t)b * TT + 256 + tt + 1) * IDIM + 64 * pks;
                    #pragma unroll
                    for (int u = 0; u < 16; ++u) xn[u] = *(const f32x4*)(xr + 4 * u);
                }
                f32x2 acc = {0.f, 0.f};
                #pragma unroll
                for (int u = 0; u < 16; ++u) {
                    acc = __builtin_elementwise_fma(wp[2*u],   pxv[u].xy, acc);
                    acc = __builtin_elementwise_fma(wp[2*u+1], pxv[u].zw, acc);
                }
                float s = octet_reduce_lane0(acc.x + acc.y);
                if (pks == 0) sz[1][tt * MIXD + pm] = s;
                if (more) {
                    #pragma unroll
                    for (int u = 0; u < 16; ++u) pxv[u] = xn[u];
                }
            }
            __syncthreads();   // h exchange + produced-row visibility
        }
    }

    // ---- fused head: zn = Whead @ h + bhead ; y = zn @ Wmix ----
    if (tid < MIXD) {
        const float* h = shp[0];                 // TT even -> final h in shp[0]
        float a0 = 0.f, a1 = 0.f, a2 = 0.f, a3 = 0.f;
        #pragma unroll
        for (int kc = 0; kc < HID / 4; ++kc) {
            f32x4 wv = *(const f32x4*)(Whead + (size_t)tid * HID + kc * 4);
            f32x4 hv4 = *(const f32x4*)(h + kc * 4);
            a0 += wv.x * hv4.x; a1 += wv.y * hv4.y;
            a2 += wv.z * hv4.z; a3 += wv.w * hv4.w;
        }
        szn[tid] = bhead[tid] + ((a0 + a1) + (a2 + a3));
    }
    __syncthreads();
    {
        const int col = tid;                     // 512 threads = 512 cols
        float acc = 0.f;
        #pragma unroll
        for (int m = 0; m < MIXD; ++m)
            acc += szn[m] * Wmix[(size_t)m * IDIM + col];
        y[(size_t)b * IDIM + col] = acc;
    }
}

extern "C" void kernel_launch(void* const* d_in, const int* in_sizes, int n_in,
                              void* d_out, int out_size, void* d_ws, size_t ws_size,
                              hipStream_t stream) {
    const float* x     = (const float*)d_in[0];
    const float* Wmix  = (const float*)d_in[1];
    const float* Wih   = (const float*)d_in[2];
    const float* Whh   = (const float*)d_in[3];
    const float* bih   = (const float*)d_in[4];
    const float* bhh   = (const float*)d_in[5];
    const float* Whead = (const float*)d_in[6];
    const float* bhead = (const float*)d_in[7];
    float* out = (float*)d_out;

    k_fused<<<BB, 512, 0, stream>>>(x, Wmix, Wih, Whh, bih, bhh, Whead, bhead, out);
}

// Round 12
// 369.862 us; speedup vs baseline: 9.1205x; 9.1205x over previous
//
#include <hip/hip_runtime.h>

#define IDIM 512
#define MIXD 32
#define HID 96
#define BB 256
#define TT 512
#define TROWS 32

typedef float f32x2 __attribute__((ext_vector_type(2)));
typedef float f32x4 __attribute__((ext_vector_type(4)));

#define EXP2(x) __builtin_amdgcn_exp2f(x)

template <int CTRL>
__device__ __forceinline__ float dpp_shl_add(float x) {
    int m = __builtin_amdgcn_update_dpp(0, __float_as_int(x), CTRL, 0xf, 0xf, true);
    return x + __int_as_float(m);
}
__device__ __forceinline__ float octet_reduce_lane0(float x) {
    x = dpp_shl_add<0x104>(x);   // row_shl:4
    x = dpp_shl_add<0x102>(x);   // row_shl:2
    x = dpp_shl_add<0x101>(x);   // row_shl:1
    return x;
}
// Pin a value in a VGPR: forbids rematerialization/spill of loop-invariant
// loads into the loop (zero instructions emitted).
__device__ __forceinline__ void pinv(f32x2 &v) { asm volatile("" : "+v"(v)); }
__device__ __forceinline__ void pinf(float &v) { asm volatile("" : "+v"(v)); }

// ---------------- K1: z = x @ W_mix^T (coalesced LDS-staged, W in regs) ----
// 256 threads: mg = tid>>3 (m-row 0..31), ks = tid&7 (64-float k-slice).
// Per block: 256 rows in 8 tiles of 32. Tile (32x512 = 64 KB) staged
// coalesced global->reg->LDS (16 f4/thread). Compute: thread reads its
// (row, ks) slice with ks-ROTATED chunk order (addr runtime, W index
// compile-time -> no dynamic reg indexing): 8 distinct addrs/instr
// (8-way mg-broadcast), 2-way bank conflict (free). W slice (32 f32x2)
// loaded once, rotated to match. Octet-DPP reduce, ks==0 stores z.
// HBM-bound design: ~12.5k cy HBM = ~12k LDS = ~7k VALU per tile-pair/CU.
__global__ __launch_bounds__(256) void k_mix(const float* __restrict__ x,
                                             const float* __restrict__ Wmix,
                                             float* __restrict__ z) {
    __shared__ __align__(16) float sx[TROWS * IDIM];   // 64 KB
    const int tid = threadIdx.x;
    const int mg = tid >> 3, ks = tid & 7;

    // W slice, rotated: w[2i],w[2i+1] hold chunk cj=(i+2ks)&15 of the slice
    f32x2 w[32];
    #pragma unroll
    for (int i = 0; i < 16; ++i) {
        const int cj = (i + 2 * ks) & 15;
        f32x4 v = *(const f32x4*)(Wmix + (size_t)mg * IDIM + ks * 64 + cj * 4);
        w[2*i] = v.xy; w[2*i+1] = v.zw;
    }

    const size_t rowbase = (size_t)blockIdx.x * 256;
    const float* xb = x + rowbase * IDIM;

    f32x4 st[16];
    #pragma unroll
    for (int i = 0; i < 16; ++i)                       // tile 0 -> regs
        st[i] = *(const f32x4*)(xb + (size_t)(tid + 256 * i) * 4);

    for (int t = 0; t < 8; ++t) {
        #pragma unroll
        for (int i = 0; i < 16; ++i)                   // regs -> LDS
            *(f32x4*)(&sx[(tid + 256 * i) * 4]) = st[i];
        __syncthreads();                               // tile t visible

        if (t + 1 < 8) {                               // issue tile t+1 loads
            const float* xn = xb + (size_t)(t + 1) * TROWS * IDIM;
            #pragma unroll
            for (int i = 0; i < 16; ++i)
                st[i] = *(const f32x4*)(xn + (size_t)(tid + 256 * i) * 4);
        }

        float* zp = z + (rowbase + (size_t)t * TROWS) * MIXD + mg;
        for (int r = 0; r < TROWS; ++r) {
            const float* rp = sx + r * IDIM + ks * 64;
            f32x2 acc = {0.f, 0.f};
            #pragma unroll
            for (int i = 0; i < 16; ++i) {
                f32x4 v = *(const f32x4*)(rp + ((i + 2 * ks) & 15) * 4);
                acc = __builtin_elementwise_fma(w[2*i],   v.xy, acc);
                acc = __builtin_elementwise_fma(w[2*i+1], v.zw, acc);
            }
            float s = octet_reduce_lane0(acc.x + acc.y);
            if (ks == 0) zp[(size_t)r * MIXD] = s;
        }
        __syncthreads();                               // done reading tile t
    }
}

// ---------------- K2: GRU scan + head (R9 structure + weight pinning) -------
// 256 threads = 4 waves. Octet per j0 serves j0, j0+32, j0+64. NEW: all 78
// weight/bias registers are asm-pinned INSIDE the step loop — R9's counters
// (VGPR_Count=108 < 132 regs of weights) prove the compiler was re-loading
// weights from cache every step; pinning forces residency and removes that
// latency chain from the 512-step critical path.
__global__ __launch_bounds__(256, 1) void k_scan(const float* __restrict__ z,
                                                 const float* __restrict__ Wih,
                                                 const float* __restrict__ Whh,
                                                 const float* __restrict__ bih,
                                                 const float* __restrict__ bhh,
                                                 const float* __restrict__ Whead,
                                                 const float* __restrict__ bhead,
                                                 const float* __restrict__ Wmix,
                                                 float* __restrict__ y) {
    const int b   = blockIdx.x;
    const int tid = threadIdx.x;
    const int j0  = tid >> 3;     // 0..31
    const int o   = tid & 7;      // 0..7
    const float L  = 1.4426950408889634f;   // log2(e)
    const float L2 = 2.8853900817779268f;   // 2*log2(e)

    __shared__ __align__(16) float sz[256 * MIXD];   // 32 KB: half of the z row
    __shared__ __align__(16) float shp[2][HID];      // h ping-pong
    __shared__ __align__(16) float szn[MIXD];

    f32x2 whr[3][6], whu[3][6], whn[3][6], wir[3][2], wiu[3][2], win[3][2];
    float br[3], bu[3], bxn[3], bhn[3];
    #pragma unroll
    for (int i = 0; i < 3; ++i) {
        const int j = j0 + 32 * i;
        #pragma unroll
        for (int c = 0; c < 3; ++c) {
            f32x4 v = *(const f32x4*)(Whh + (size_t)(j        ) * HID + o * 12 + c * 4);
            v *= L;  whr[i][2*c] = v.xy; whr[i][2*c+1] = v.zw;
        }
        #pragma unroll
        for (int c = 0; c < 3; ++c) {
            f32x4 v = *(const f32x4*)(Whh + (size_t)(j +   HID) * HID + o * 12 + c * 4);
            v *= L;  whu[i][2*c] = v.xy; whu[i][2*c+1] = v.zw;
        }
        #pragma unroll
        for (int c = 0; c < 3; ++c) {
            f32x4 v = *(const f32x4*)(Whh + (size_t)(j + 2*HID) * HID + o * 12 + c * 4);
            v *= L2; whn[i][2*c] = v.xy; whn[i][2*c+1] = v.zw;
        }
        {
            f32x4 v = *(const f32x4*)(Wih + (size_t)(j        ) * MIXD + o * 4);
            v *= L;  wir[i][0] = v.xy; wir[i][1] = v.zw;
        }
        {
            f32x4 v = *(const f32x4*)(Wih + (size_t)(j +   HID) * MIXD + o * 4);
            v *= L;  wiu[i][0] = v.xy; wiu[i][1] = v.zw;
        }
        {
            f32x4 v = *(const f32x4*)(Wih + (size_t)(j + 2*HID) * MIXD + o * 4);
            v *= L2; win[i][0] = v.xy; win[i][1] = v.zw;
        }
        br[i]  = (o == 0) ? L  * (bih[j]       + bhh[j])       : 0.f;
        bu[i]  = (o == 0) ? L  * (bih[j + HID] + bhh[j + HID]) : 0.f;
        bxn[i] = (o == 0) ? L2 * bih[j + 2*HID] : 0.f;
        bhn[i] = (o == 0) ? L2 * bhh[j + 2*HID] : 0.f;
    }

    float hown[3] = {0.f, 0.f, 0.f};
    if (tid < HID) shp[0][tid] = 0.f;

    const f32x4* zb4 = (const f32x4*)(z + (size_t)b * TT * MIXD);
    f32x4* sz4 = (f32x4*)sz;

    for (int c = 0; c < TT / 256; ++c) {
        #pragma unroll
        for (int i = 0; i < 8; ++i)
            sz4[tid + 256 * i] = zb4[c * 2048 + tid + 256 * i];
        __syncthreads();

        for (int tt = 0; tt < 256; ++tt) {
            // pin all loop-invariant weights in VGPRs (no remat, no spill)
            #pragma unroll
            for (int i = 0; i < 3; ++i) {
                #pragma unroll
                for (int k = 0; k < 6; ++k) { pinv(whr[i][k]); pinv(whu[i][k]); pinv(whn[i][k]); }
                pinv(wir[i][0]); pinv(wir[i][1]);
                pinv(wiu[i][0]); pinv(wiu[i][1]);
                pinv(win[i][0]); pinv(win[i][1]);
                pinf(br[i]); pinf(bu[i]); pinf(bxn[i]); pinf(bhn[i]);
            }

            const int t = (c << 8) + tt;
            const float* hr = shp[t & 1];
            float*       hw = shp[(t + 1) & 1];

            const f32x4 z4 = *(const f32x4*)(sz + tt * MIXD + o * 4);
            const f32x4 h0 = *(const f32x4*)(hr + o * 12);
            const f32x4 h1 = *(const f32x4*)(hr + o * 12 + 4);
            const f32x4 h2 = *(const f32x4*)(hr + o * 12 + 8);
            const f32x2 hh[6] = { h0.xy, h0.zw, h1.xy, h1.zw, h2.xy, h2.zw };

            float hv[3];
            #pragma unroll
            for (int i = 0; i < 3; ++i) {
                f32x2 aR  = {br[i],  0.f}, aU  = {bu[i],  0.f};
                f32x2 aXN = {bxn[i], 0.f}, aHN = {bhn[i], 0.f};

                aR  = __builtin_elementwise_fma(wir[i][0], z4.xy, aR);
                aR  = __builtin_elementwise_fma(wir[i][1], z4.zw, aR);
                aU  = __builtin_elementwise_fma(wiu[i][0], z4.xy, aU);
                aU  = __builtin_elementwise_fma(wiu[i][1], z4.zw, aU);
                aXN = __builtin_elementwise_fma(win[i][0], z4.xy, aXN);
                aXN = __builtin_elementwise_fma(win[i][1], z4.zw, aXN);

                #pragma unroll
                for (int k = 0; k < 6; ++k) {
                    aR  = __builtin_elementwise_fma(whr[i][k], hh[k], aR);
                    aU  = __builtin_elementwise_fma(whu[i][k], hh[k], aU);
                    aHN = __builtin_elementwise_fma(whn[i][k], hh[k], aHN);
                }

                float sR  = octet_reduce_lane0(aR.x  + aR.y);
                float sU  = octet_reduce_lane0(aU.x  + aU.y);
                float sXN = octet_reduce_lane0(aXN.x + aXN.y);
                float sHN = octet_reduce_lane0(aHN.x + aHN.y);

                float r = __builtin_amdgcn_rcpf(1.f + EXP2(-sR));
                float u = __builtin_amdgcn_rcpf(1.f + EXP2(-sU));
                float n = 1.f - 2.f * __builtin_amdgcn_rcpf(1.f + EXP2(sXN + r * sHN));
                hv[i] = u * (hown[i] - n) + n;   // lane0 correct; others garbage
                hown[i] = hv[i];
            }
            if (o == 0) {
                hw[j0]      = hv[0];
                hw[j0 + 32] = hv[1];
                hw[j0 + 64] = hv[2];
            }
            __syncthreads();                    // the ONLY barrier per step
        }
    }

    // ---- fused head: zn = Whead @ h + bhead ; y = zn @ Wmix ----
    if (tid < MIXD) {
        const float* h = shp[0];                 // TT even -> final h in shp[0]
        float a0 = 0.f, a1 = 0.f, a2 = 0.f, a3 = 0.f;
        #pragma unroll
        for (int kc = 0; kc < HID / 4; ++kc) {
            f32x4 wv = *(const f32x4*)(Whead + (size_t)tid * HID + kc * 4);
            f32x4 hv4 = *(const f32x4*)(h + kc * 4);
            a0 += wv.x * hv4.x; a1 += wv.y * hv4.y;
            a2 += wv.z * hv4.z; a3 += wv.w * hv4.w;
        }
        szn[tid] = bhead[tid] + ((a0 + a1) + (a2 + a3));
    }
    __syncthreads();
    #pragma unroll
    for (int rep = 0; rep < 2; ++rep) {
        const int col = tid + 256 * rep;
        float acc = 0.f;
        #pragma unroll
        for (int m = 0; m < MIXD; ++m)
            acc += szn[m] * Wmix[(size_t)m * IDIM + col];
        y[(size_t)b * IDIM + col] = acc;
    }
}

extern "C" void kernel_launch(void* const* d_in, const int* in_sizes, int n_in,
                              void* d_out, int out_size, void* d_ws, size_t ws_size,
                              hipStream_t stream) {
    const float* x     = (const float*)d_in[0];
    const float* Wmix  = (const float*)d_in[1];
    const float* Wih   = (const float*)d_in[2];
    const float* Whh   = (const float*)d_in[3];
    const float* bih   = (const float*)d_in[4];
    const float* bhh   = (const float*)d_in[5];
    const float* Whead = (const float*)d_in[6];
    const float* bhead = (const float*)d_in[7];
    float* out = (float*)d_out;

    float* z = (float*)d_ws;   // [B*T, 32] = 16.78 MB

    k_mix <<<512, 256, 0, stream>>>(x, Wmix, z);
    k_scan<<<BB,  256, 0, stream>>>(z, Wih, Whh, bih, bhh, Whead, bhead, Wmix, out);
}